// Round 2
// baseline (792.717 us; speedup 1.0000x reference)
//
#include <hip/hip_runtime.h>

// Problem constants
#define N_ROWS 65536   // 32*2048 rows
#define DDIM   64
#define KCODES 2048
#define NB     128     // rows per block
#define CHUNK  256     // codes per LDS chunk
#define NCHUNK (KCODES / CHUNK)
#define TAU    0.05f   // top-2 gap threshold for fp64 refinement

// d_out layout (float32, concatenated in reference return order)
#define Q_OFF    ((size_t)0)
#define ENC_OFF  ((size_t)N_ROWS * DDIM)                 // 4194304
#define IDX_OFF  (ENC_OFF + (size_t)N_ROWS * KCODES)     // 138412032
#define LOSS_OFF (IDX_OFF + (size_t)N_ROWS)              // 138477568
#define INV_ND (1.0f / ((float)N_ROWS * (float)DDIM))

// d_ws layout (bytes):
//   [0, 524288)        : bf16 B image, 8 chunks x { hi[256][64], lo[256][64] } shorts
//                        (k index stored XOR-swizzled: kk = k ^ ((code&7)<<3))
//   [524288, 532480)   : esq, 2048 floats
//   [532480, 794624)   : flags, 65536 ints
#define WS_ESQ_OFF   (524288)
#define WS_FLAGS_OFF (532480)

typedef __attribute__((ext_vector_type(8))) short short8;
typedef __attribute__((ext_vector_type(4))) float f32x4;

__device__ __forceinline__ unsigned short f2bf(float f) {
    unsigned u = __float_as_uint(f);
    u += 0x7FFFu + ((u >> 16) & 1u);
    return (unsigned short)(u >> 16);
}
__device__ __forceinline__ float bf2f(unsigned short h) {
    return __uint_as_float(((unsigned)h) << 16);
}

// Streaming zero of the one-hot encodings slab (512 MiB). Shape-matched to the
// rocclr fill that demonstrably hits 6.2 TB/s on this buffer: grid-stride
// float4 stores, no barriers, no vmcnt coupling with any compute.
__global__ void vq_zero(float* __restrict__ out) {
    const size_t stride = (size_t)gridDim.x * blockDim.x;
    size_t i = (size_t)blockIdx.x * blockDim.x + threadIdx.x;
    const size_t n4 = (size_t)N_ROWS * KCODES / 4;   // 33554432 float4s
    float4 z = make_float4(0.f, 0.f, 0.f, 0.f);
    float4* enc = (float4*)(out + ENC_OFF);
    for (; i < n4; i += stride) enc[i] = z;
}

// Split embeddings into bf16 hi/lo (swizzled layout) + ||e||^2 + zero loss slot.
__global__ void vq_prep(const float* __restrict__ emb, char* __restrict__ ws,
                        float* __restrict__ out) {
    int t = blockIdx.x * 256 + threadIdx.x;        // [0, 131072)
    int code = t & (KCODES - 1);
    int d    = t >> 11;
    float v = emb[(size_t)d * KCODES + code];
    unsigned short hi = f2bf(v);
    unsigned short lo = f2bf(v - bf2f(hi));
    int ch = code >> 8;
    int lc = code & 255;
    int kk = d ^ ((code & 7) << 3);
    short* base = (short*)ws + (size_t)ch * 32768 + lc * 64 + kk;
    base[0]     = (short)hi;
    base[16384] = (short)lo;
    if (t < KCODES) {
        float s = 0.f;
        for (int dd = 0; dd < DDIM; ++dd) {
            float e = emb[(size_t)dd * KCODES + t];
            s += e * e;
        }
        ((float*)(ws + WS_ESQ_OFF))[t] = s;
    }
    if (t == 0) out[LOSS_OFF] = 0.f;
}

__launch_bounds__(256, 2)
__global__ void vq_main(const float* __restrict__ x, const float* __restrict__ emb,
                        const char* __restrict__ ws, int* __restrict__ flags,
                        float* __restrict__ out) {
    __shared__ __align__(16) short Bs[32768];   // 64 KB: hi[256][64] then lo[256][64]
    const int tid = threadIdx.x;
    const int l = tid & 63, w = tid >> 6;
    const int q = l >> 4, c = l & 15;
    const int r0 = blockIdx.x * NB;
    const float* esq = (const float*)(ws + WS_ESQ_OFF);

    // A fragments: this wave's 32 rows, bf16 hi/lo, resident in registers.
    // A-operand layout: lane holds A[m = l&15][k = q*8 + j].
    short8 ah0[2], ah1[2], al0[2], al1[2];
    #pragma unroll
    for (int rt = 0; rt < 2; ++rt) {
        int row = r0 + w * 32 + rt * 16 + c;
        const float4* xr = (const float4*)(x + (size_t)row * DDIM);
        float4 f0 = xr[q * 2],     f1 = xr[q * 2 + 1];
        float4 f2 = xr[8 + q * 2], f3 = xr[8 + q * 2 + 1];
        float a0[8] = {f0.x,f0.y,f0.z,f0.w,f1.x,f1.y,f1.z,f1.w};
        float a1[8] = {f2.x,f2.y,f2.z,f2.w,f3.x,f3.y,f3.z,f3.w};
        #pragma unroll
        for (int j = 0; j < 8; ++j) {
            unsigned short h0 = f2bf(a0[j]);
            ah0[rt][j] = (short)h0;
            al0[rt][j] = (short)f2bf(a0[j] - bf2f(h0));
            unsigned short h1 = f2bf(a1[j]);
            ah1[rt][j] = (short)h1;
            al1[rt][j] = (short)f2bf(a1[j] - bf2f(h1));
        }
    }

    float m1[8], m2[8]; int i1[8];
    #pragma unroll
    for (int s = 0; s < 8; ++s) { m1[s] = 3.4e38f; m2[s] = 3.4e38f; i1[s] = 0; }

    for (int ch = 0; ch < NCHUNK; ++ch) {
        const int kc = ch * CHUNK;
        __syncthreads();   // readers of previous chunk done
        // Stage 64 KB bf16 chunk from ws (linear, conflict-free)
        {
            const int4* g4 = (const int4*)(ws + (size_t)ch * 65536);
            int4* s4 = (int4*)Bs;
            #pragma unroll
            for (int i = 0; i < 16; ++i) s4[i * 256 + tid] = g4[i * 256 + tid];
        }
        __syncthreads();

        // 16 code-tiles of 16; 3-term bf16-split MFMA (hi*hi + hi*lo + lo*hi)
        const int swz = (c & 7) << 3;
        for (int t = 0; t < 16; ++t) {
            int codeL = t * 16 + c;
            const short* ph = Bs + codeL * 64;
            const short* pl = ph + 16384;
            int k0 = (q * 8) ^ swz;
            int k1 = (32 + q * 8) ^ swz;
            short8 bh0 = *(const short8*)(ph + k0);
            short8 bh1 = *(const short8*)(ph + k1);
            short8 bl0 = *(const short8*)(pl + k0);
            short8 bl1 = *(const short8*)(pl + k1);
            int   kidx = kc + t * 16 + c;
            float eq   = esq[kidx];
            #pragma unroll
            for (int rt = 0; rt < 2; ++rt) {
                f32x4 acc = {0.f, 0.f, 0.f, 0.f};
                acc = __builtin_amdgcn_mfma_f32_16x16x32_bf16(ah0[rt], bh0, acc, 0, 0, 0);
                acc = __builtin_amdgcn_mfma_f32_16x16x32_bf16(ah1[rt], bh1, acc, 0, 0, 0);
                acc = __builtin_amdgcn_mfma_f32_16x16x32_bf16(ah0[rt], bl0, acc, 0, 0, 0);
                acc = __builtin_amdgcn_mfma_f32_16x16x32_bf16(ah1[rt], bl1, acc, 0, 0, 0);
                acc = __builtin_amdgcn_mfma_f32_16x16x32_bf16(al0[rt], bh0, acc, 0, 0, 0);
                acc = __builtin_amdgcn_mfma_f32_16x16x32_bf16(al1[rt], bh1, acc, 0, 0, 0);
                #pragma unroll
                for (int g = 0; g < 4; ++g) {
                    float dist = fmaf(-2.f, acc[g], eq);   // + ||x||^2 omitted (row-const)
                    int s = rt * 4 + g;
                    bool better = dist < m1[s];
                    m2[s] = fminf(m2[s], fmaxf(m1[s], dist));
                    m1[s] = fminf(m1[s], dist);
                    i1[s] = better ? kidx : i1[s];
                }
            }
        }
    }

    __syncthreads();   // Bs now dead -> reuse for reduction
    float* red  = (float*)Bs;                 // [128 rows][16 cols][3]: m1, idx, m2
    int*   indS = (int*)(red + 6144);         // [128]
    float* lred = red + 6144 + 128;           // [4]

    // C/D layout: col = l&15, row = q*4 + reg  [m89]
    #pragma unroll
    for (int rt = 0; rt < 2; ++rt)
        #pragma unroll
        for (int g = 0; g < 4; ++g) {
            int lrow = w * 32 + rt * 16 + q * 4 + g;
            float* p = red + (size_t)(lrow * 16 + c) * 3;
            p[0] = m1[rt * 4 + g];
            p[1] = (float)i1[rt * 4 + g];
            p[2] = m2[rt * 4 + g];
        }
    __syncthreads();

    // Per-row scan across the 16 col-lanes: global top-2 + index (low-idx tiebreak)
    if (tid < NB) {
        int row = tid;
        const float* p = red + (size_t)row * 48;
        float gm1 = 3.4e38f; int gi1 = 0x7fffffff; int wt = -1;
        for (int t = 0; t < 16; ++t) {
            float v  = p[t * 3 + 0];
            int   iv = (int)p[t * 3 + 1];
            if (v < gm1 || (v == gm1 && iv < gi1)) { gm1 = v; gi1 = iv; wt = t; }
        }
        float gm2 = 3.4e38f;
        for (int t = 0; t < 16; ++t) {
            float cand = (t == wt) ? p[t * 3 + 2] : p[t * 3 + 0];
            gm2 = fminf(gm2, cand);
        }
        int gr = r0 + row;
        out[IDX_OFF + gr] = (float)gi1;
        flags[gr] = (gm2 - gm1 < TAU) ? 1 : 0;
        indS[row] = gi1;
        // zeros were written by vq_zero (prior kernel) -> ordering by dispatch
        out[ENC_OFF + (size_t)gr * KCODES + gi1] = 1.0f;
    }
    __syncthreads();

    // Quantized rows + commitment-loss partial (exact fp32 inputs)
    float lpart = 0.f;
    for (int i = tid; i < NB * (DDIM / 4); i += 256) {
        int row = i >> 4;
        int d4  = (i & 15) << 2;
        int idx = indS[row];
        int gr  = r0 + row;
        float4 qv;
        qv.x = emb[(size_t)(d4 + 0) * KCODES + idx];
        qv.y = emb[(size_t)(d4 + 1) * KCODES + idx];
        qv.z = emb[(size_t)(d4 + 2) * KCODES + idx];
        qv.w = emb[(size_t)(d4 + 3) * KCODES + idx];
        *(float4*)(out + Q_OFF + (size_t)gr * DDIM + d4) = qv;
        float4 xv = *(const float4*)(x + (size_t)gr * DDIM + d4);
        float dx = qv.x - xv.x, dy = qv.y - xv.y, dz = qv.z - xv.z, dw = qv.w - xv.w;
        lpart += dx * dx + dy * dy + dz * dz + dw * dw;
    }
    #pragma unroll
    for (int o = 32; o > 0; o >>= 1) lpart += __shfl_down(lpart, o);
    if ((tid & 63) == 0) lred[tid >> 6] = lpart;
    __syncthreads();
    if (tid == 0)
        atomicAdd(out + LOSS_OFF, (lred[0] + lred[1] + lred[2] + lred[3]) * INV_ND);
}

// Exact fp64 argmin for rows whose top-2 gap was below TAU.
__global__ void vq_refine(const float* __restrict__ x, const float* __restrict__ emb,
                          const int* __restrict__ flags, float* __restrict__ out) {
    const int lane = threadIdx.x & 63;
    const int wid  = threadIdx.x >> 6;
    for (int rr = 0; rr < 8; ++rr) {
        int row = (blockIdx.x * 4 + wid) * 8 + rr;
        if (flags[row] == 0) continue;                 // wave-uniform
        const float* xr = x + (size_t)row * DDIM;
        double best = 1e300; int bidx = 0x7fffffff;
        for (int k = lane; k < KCODES; k += 64) {
            double s = 0.0, ee = 0.0;
            for (int d = 0; d < DDIM; ++d) {
                double e = (double)emb[(size_t)d * KCODES + k];
                s  = fma((double)xr[d], e, s);
                ee = fma(e, e, ee);
            }
            double dist = ee - 2.0 * s;
            if (dist < best) { best = dist; bidx = k; }
        }
        #pragma unroll
        for (int o = 32; o > 0; o >>= 1) {
            double ob = __shfl_down(best, o);
            int    oi = __shfl_down(bidx, o);
            if (ob < best || (ob == best && oi < bidx)) { best = ob; bidx = oi; }
        }
        bidx = __shfl(bidx, 0);
        int oldIdx = (int)out[IDX_OFF + row];
        if (bidx == oldIdx) continue;
        if (lane == 0) {
            out[IDX_OFF + row] = (float)bidx;
            out[ENC_OFF + (size_t)row * KCODES + oldIdx] = 0.f;
            out[ENC_OFF + (size_t)row * KCODES + bidx]   = 1.f;
        }
        float eN = emb[(size_t)lane * KCODES + bidx];
        float eO = emb[(size_t)lane * KCODES + oldIdx];
        float xv = xr[lane];
        out[Q_OFF + (size_t)row * DDIM + lane] = eN;
        float dn = eN - xv, dod = eO - xv;
        float delta = dn * dn - dod * dod;
        #pragma unroll
        for (int o = 32; o > 0; o >>= 1) delta += __shfl_down(delta, o);
        if (lane == 0) atomicAdd(out + LOSS_OFF, delta * INV_ND);
    }
}

extern "C" void kernel_launch(void* const* d_in, const int* in_sizes, int n_in,
                              void* d_out, int out_size, void* d_ws, size_t ws_size,
                              hipStream_t stream) {
    const float* x   = (const float*)d_in[0];   // [65536, 64]
    const float* emb = (const float*)d_in[1];   // [64, 2048]
    float* out   = (float*)d_out;
    char*  ws    = (char*)d_ws;
    int*   flags = (int*)(ws + WS_FLAGS_OFF);
    // vq_zero first: its 512 MiB stream would evict prep's ws image from L2;
    // running it before prep keeps ws L2-hot for vq_main's staging reads.
    hipLaunchKernelGGL(vq_zero,   dim3(2048),        dim3(256), 0, stream, out);
    hipLaunchKernelGGL(vq_prep,   dim3(512),         dim3(256), 0, stream, emb, ws, out);
    hipLaunchKernelGGL(vq_main,   dim3(N_ROWS / NB), dim3(256), 0, stream, x, emb, ws, flags, out);
    hipLaunchKernelGGL(vq_refine, dim3(N_ROWS / 32), dim3(256), 0, stream, x, emb, flags, out);
}

// Round 3
// 708.597 us; speedup vs baseline: 1.1187x; 1.1187x over previous
//
#include <hip/hip_runtime.h>

// Problem constants
#define N_ROWS 65536   // 32*2048 rows
#define DDIM   64
#define KCODES 2048
#define NB     128     // rows per block
#define CHUNK  256     // codes per LDS chunk
#define NCHUNK (KCODES / CHUNK)
#define TAU    0.05f   // top-2 gap threshold for fp64 refinement

// d_out layout (float32, concatenated in reference return order)
#define Q_OFF    ((size_t)0)
#define ENC_OFF  ((size_t)N_ROWS * DDIM)                 // 4194304
#define IDX_OFF  (ENC_OFF + (size_t)N_ROWS * KCODES)     // 138412032
#define LOSS_OFF (IDX_OFF + (size_t)N_ROWS)              // 138477568
#define INV_ND (1.0f / ((float)N_ROWS * (float)DDIM))

// d_ws layout (bytes):
//   [0, 524288)        : bf16 B image, 8 chunks x { hi[256][64], lo[256][64] } shorts
//                        (k index stored XOR-swizzled: kk = k ^ ((code&7)<<3))
//   [524288, 532480)   : esq, 2048 floats
//   [532480, 794624)   : flags, 65536 ints
#define WS_ESQ_OFF   (524288)
#define WS_FLAGS_OFF (532480)

typedef __attribute__((ext_vector_type(8))) short short8;
typedef __attribute__((ext_vector_type(4))) float f32x4;

__device__ __forceinline__ unsigned short f2bf(float f) {
    unsigned u = __float_as_uint(f);
    u += 0x7FFFu + ((u >> 16) & 1u);
    return (unsigned short)(u >> 16);
}
__device__ __forceinline__ float bf2f(unsigned short h) {
    return __uint_as_float(((unsigned)h) << 16);
}

// Split embeddings into bf16 hi/lo (swizzled layout) + ||e||^2 + zero loss slot.
__global__ void vq_prep(const float* __restrict__ emb, char* __restrict__ ws,
                        float* __restrict__ out) {
    int t = blockIdx.x * 256 + threadIdx.x;        // [0, 131072)
    int code = t & (KCODES - 1);
    int d    = t >> 11;
    float v = emb[(size_t)d * KCODES + code];
    unsigned short hi = f2bf(v);
    unsigned short lo = f2bf(v - bf2f(hi));
    int ch = code >> 8;
    int lc = code & 255;
    int kk = d ^ ((code & 7) << 3);
    short* base = (short*)ws + (size_t)ch * 32768 + lc * 64 + kk;
    base[0]     = (short)hi;
    base[16384] = (short)lo;
    if (t < KCODES) {
        float s = 0.f;
        for (int dd = 0; dd < DDIM; ++dd) {
            float e = emb[(size_t)dd * KCODES + t];
            s += e * e;
        }
        ((float*)(ws + WS_ESQ_OFF))[t] = s;
    }
    if (t == 0) out[LOSS_OFF] = 0.f;
}

__launch_bounds__(256, 2)
__global__ void vq_main(const float* __restrict__ x, const float* __restrict__ emb,
                        const char* __restrict__ ws, int* __restrict__ flags,
                        float* __restrict__ out) {
    __shared__ __align__(16) short Bs[32768];   // 64 KB: hi[256][64] then lo[256][64]
    const int tid = threadIdx.x;
    const int l = tid & 63, w = tid >> 6;
    const int q = l >> 4, c = l & 15;
    const int r0 = blockIdx.x * NB;
    const float* esq = (const float*)(ws + WS_ESQ_OFF);

    // A fragments: this wave's 32 rows, bf16 hi/lo, resident in registers.
    // A-operand layout: lane holds A[m = l&15][k = q*8 + j].
    short8 ah0[2], ah1[2], al0[2], al1[2];
    #pragma unroll
    for (int rt = 0; rt < 2; ++rt) {
        int row = r0 + w * 32 + rt * 16 + c;
        const float4* xr = (const float4*)(x + (size_t)row * DDIM);
        float4 f0 = xr[q * 2],     f1 = xr[q * 2 + 1];
        float4 f2 = xr[8 + q * 2], f3 = xr[8 + q * 2 + 1];
        float a0[8] = {f0.x,f0.y,f0.z,f0.w,f1.x,f1.y,f1.z,f1.w};
        float a1[8] = {f2.x,f2.y,f2.z,f2.w,f3.x,f3.y,f3.z,f3.w};
        #pragma unroll
        for (int j = 0; j < 8; ++j) {
            unsigned short h0 = f2bf(a0[j]);
            ah0[rt][j] = (short)h0;
            al0[rt][j] = (short)f2bf(a0[j] - bf2f(h0));
            unsigned short h1 = f2bf(a1[j]);
            ah1[rt][j] = (short)h1;
            al1[rt][j] = (short)f2bf(a1[j] - bf2f(h1));
        }
    }

    // Per-slot top-3 values + top-2 indices. Slots = 8 distinct output rows.
    float m1[8], m2[8], m3[8]; int i1[8], i2[8];
    #pragma unroll
    for (int s = 0; s < 8; ++s) {
        m1[s] = 3.4e38f; m2[s] = 3.4e38f; m3[s] = 3.4e38f; i1[s] = 0; i2[s] = 0;
    }

    for (int ch = 0; ch < NCHUNK; ++ch) {
        const int kc = ch * CHUNK;
        __syncthreads();   // readers of previous chunk done; prior stores drained
        // Stage 64 KB bf16 chunk from ws (linear, conflict-free)
        {
            const int4* g4 = (const int4*)(ws + (size_t)ch * 65536);
            int4* s4 = (int4*)Bs;
            #pragma unroll
            for (int i = 0; i < 16; ++i) s4[i * 256 + tid] = g4[i * 256 + tid];
        }
        __syncthreads();

        // Fire-and-forget zero-stores for this chunk's one-hot slab (128 rows x 256 codes).
        // They drain under the MFMA work; next barrier's vmcnt(0) orders them
        // before the final 1.0 write.
        {
            float4 z = make_float4(0.f, 0.f, 0.f, 0.f);
            float* ebase = out + ENC_OFF + (size_t)r0 * KCODES + kc;
            #pragma unroll
            for (int j = 0; j < 32; ++j) {
                int s   = j * 256 + tid;
                int row = s >> 6;
                int c4  = s & 63;
                *(float4*)(ebase + (size_t)row * KCODES + (c4 << 2)) = z;
            }
        }

        // 16 code-tiles of 16; 3-term bf16-split MFMA (hi*hi + hi*lo + lo*hi)
        const int swz = (c & 7) << 3;
        for (int t = 0; t < 16; ++t) {
            int codeL = t * 16 + c;
            const short* ph = Bs + codeL * 64;
            const short* pl = ph + 16384;
            int k0 = (q * 8) ^ swz;
            int k1 = (32 + q * 8) ^ swz;
            short8 bh0 = *(const short8*)(ph + k0);
            short8 bh1 = *(const short8*)(ph + k1);
            short8 bl0 = *(const short8*)(pl + k0);
            short8 bl1 = *(const short8*)(pl + k1);
            int   kidx = kc + t * 16 + c;
            float eq   = esq[kidx];
            #pragma unroll
            for (int rt = 0; rt < 2; ++rt) {
                f32x4 acc = {0.f, 0.f, 0.f, 0.f};
                acc = __builtin_amdgcn_mfma_f32_16x16x32_bf16(ah0[rt], bh0, acc, 0, 0, 0);
                acc = __builtin_amdgcn_mfma_f32_16x16x32_bf16(ah1[rt], bh1, acc, 0, 0, 0);
                acc = __builtin_amdgcn_mfma_f32_16x16x32_bf16(ah0[rt], bl0, acc, 0, 0, 0);
                acc = __builtin_amdgcn_mfma_f32_16x16x32_bf16(ah1[rt], bl1, acc, 0, 0, 0);
                acc = __builtin_amdgcn_mfma_f32_16x16x32_bf16(al0[rt], bh0, acc, 0, 0, 0);
                acc = __builtin_amdgcn_mfma_f32_16x16x32_bf16(al1[rt], bh1, acc, 0, 0, 0);
                #pragma unroll
                for (int g = 0; g < 4; ++g) {
                    float dist = fmaf(-2.f, acc[g], eq);   // + ||x||^2 omitted (row-const)
                    int s = rt * 4 + g;
                    bool b1 = dist < m1[s];
                    bool b2 = dist < m2[s];
                    bool b3 = dist < m3[s];
                    // top-3 insert (strict < keeps lower kidx on ties; kidx ascends per lane)
                    m3[s] = b2 ? m2[s] : (b3 ? dist : m3[s]);
                    m2[s] = b1 ? m1[s] : (b2 ? dist : m2[s]);
                    i2[s] = b1 ? i1[s] : (b2 ? kidx : i2[s]);
                    m1[s] = b1 ? dist : m1[s];
                    i1[s] = b1 ? kidx : i1[s];
                }
            }
        }
    }

    __syncthreads();   // drains last zero-stores; Bs now dead -> reuse for reduction
    float* red  = (float*)Bs;                 // [128 rows][16 cols][5]: m1,i1,m2,i2,m3
    int*   indS = (int*)(red + 10240);        // [128]
    float* lred = red + 10240 + 128;          // [4]

    // C/D layout: col = l&15, row = q*4 + reg  [m89]
    #pragma unroll
    for (int rt = 0; rt < 2; ++rt)
        #pragma unroll
        for (int g = 0; g < 4; ++g) {
            int lrow = w * 32 + rt * 16 + q * 4 + g;
            float* p = red + (size_t)(lrow * 16 + c) * 5;
            int s = rt * 4 + g;
            p[0] = m1[s];
            p[1] = (float)i1[s];
            p[2] = m2[s];
            p[3] = (float)i2[s];
            p[4] = m3[s];
        }
    __syncthreads();

    // Per-row scan across the 16 col-lanes: global top-3 values + top-2 indices.
    // Any code outside {gi1,gi2} has approx dist >= gm3; if gm3-gm1 >= TAU the
    // exact argmin is provably in {gi1,gi2} -> cheap pair-mode refine.
    if (tid < NB) {
        int row = tid;
        const float* p = red + (size_t)row * 80;
        float gm1 = 3.4e38f, gm2v = 3.4e38f, gm3 = 3.4e38f;
        int gi1 = 0x7fffffff, gi2 = 0x7fffffff;
        for (int t = 0; t < 16; ++t) {
            float v1 = p[t * 5 + 0], v2 = p[t * 5 + 2], v3 = p[t * 5 + 4];
            int   j1 = (int)p[t * 5 + 1], j2 = (int)p[t * 5 + 3];
            // insert (v1, j1)
            if (v1 < gm1 || (v1 == gm1 && j1 < gi1)) {
                gm3 = gm2v; gm2v = gm1; gi2 = gi1; gm1 = v1; gi1 = j1;
            } else if (v1 < gm2v || (v1 == gm2v && j1 < gi2)) {
                gm3 = gm2v; gm2v = v1; gi2 = j1;
            } else if (v1 < gm3) gm3 = v1;
            // insert (v2, j2)  (v2 >= v1, so it can't displace what v1 just set wrongly)
            if (v2 < gm1 || (v2 == gm1 && j2 < gi1)) {
                gm3 = gm2v; gm2v = gm1; gi2 = gi1; gm1 = v2; gi1 = j2;
            } else if (v2 < gm2v || (v2 == gm2v && j2 < gi2)) {
                gm3 = gm2v; gm2v = v2; gi2 = j2;
            } else if (v2 < gm3) gm3 = v2;
            // v3 can only be a global 3rd-value candidate (its col already holds 2 better)
            if (v3 < gm3) gm3 = v3;
        }
        int gr = r0 + row;
        out[IDX_OFF + gr] = (float)gi1;
        int f = 0;
        if (gm2v - gm1 < TAU) f = (gm3 - gm1 < TAU) ? 1 : ((gi2 << 2) | 2);
        flags[gr] = f;
        indS[row] = gi1;
        out[ENC_OFF + (size_t)gr * KCODES + gi1] = 1.0f;  // after zero-drain barrier
    }
    __syncthreads();

    // Quantized rows + commitment-loss partial (exact fp32 inputs)
    float lpart = 0.f;
    for (int i = tid; i < NB * (DDIM / 4); i += 256) {
        int row = i >> 4;
        int d4  = (i & 15) << 2;
        int idx = indS[row];
        int gr  = r0 + row;
        float4 qv;
        qv.x = emb[(size_t)(d4 + 0) * KCODES + idx];
        qv.y = emb[(size_t)(d4 + 1) * KCODES + idx];
        qv.z = emb[(size_t)(d4 + 2) * KCODES + idx];
        qv.w = emb[(size_t)(d4 + 3) * KCODES + idx];
        *(float4*)(out + Q_OFF + (size_t)gr * DDIM + d4) = qv;
        float4 xv = *(const float4*)(x + (size_t)gr * DDIM + d4);
        float dx = qv.x - xv.x, dy = qv.y - xv.y, dz = qv.z - xv.z, dw = qv.w - xv.w;
        lpart += dx * dx + dy * dy + dz * dz + dw * dw;
    }
    #pragma unroll
    for (int o = 32; o > 0; o >>= 1) lpart += __shfl_down(lpart, o);
    if ((tid & 63) == 0) lred[tid >> 6] = lpart;
    __syncthreads();
    if (tid == 0)
        atomicAdd(out + LOSS_OFF, (lred[0] + lred[1] + lred[2] + lred[3]) * INV_ND);
}

// Exact fp64 argmin for rows whose top-2 gap was below TAU.
// flags: 0 = clean; 1 = full 2048-code fp64 scan (two gaps below TAU, rare);
//        (i2<<2)|2 = pair mode: exact compare {current idx, i2} only.
__global__ void vq_refine(const float* __restrict__ x, const float* __restrict__ emb,
                          const int* __restrict__ flags, float* __restrict__ out) {
    const int lane = threadIdx.x & 63;
    const int wid  = threadIdx.x >> 6;
    for (int rr = 0; rr < 8; ++rr) {
        int row = (blockIdx.x * 4 + wid) * 8 + rr;
        int f = flags[row];
        if (f == 0) continue;                 // wave-uniform
        const float* xr = x + (size_t)row * DDIM;
        int oldIdx = (int)out[IDX_OFF + row];
        int bidx;
        if (f != 1) {
            // Pair mode: lane = dim; fp64 dist = ||e||^2 - 2 x.e (same formula as scan)
            int cand = f >> 2;
            double xd = (double)xr[lane];
            double ea = (double)emb[(size_t)lane * KCODES + oldIdx];
            double eb = (double)emb[(size_t)lane * KCODES + cand];
            double sa = xd * ea, sb = xd * eb;
            double qa = ea * ea, qb = eb * eb;
            #pragma unroll
            for (int o = 32; o > 0; o >>= 1) {
                sa += __shfl_down(sa, o);
                sb += __shfl_down(sb, o);
                qa += __shfl_down(qa, o);
                qb += __shfl_down(qb, o);
            }
            double dA = __shfl(qa - 2.0 * sa, 0);
            double dB = __shfl(qb - 2.0 * sb, 0);
            bidx = (dB < dA || (dB == dA && cand < oldIdx)) ? cand : oldIdx;
        } else {
            double best = 1e300; int bi = 0x7fffffff;
            for (int k = lane; k < KCODES; k += 64) {
                double s = 0.0, ee = 0.0;
                for (int d = 0; d < DDIM; ++d) {
                    double e = (double)emb[(size_t)d * KCODES + k];
                    s  = fma((double)xr[d], e, s);
                    ee = fma(e, e, ee);
                }
                double dist = ee - 2.0 * s;
                if (dist < best) { best = dist; bi = k; }
            }
            #pragma unroll
            for (int o = 32; o > 0; o >>= 1) {
                double ob = __shfl_down(best, o);
                int    oi = __shfl_down(bi, o);
                if (ob < best || (ob == best && oi < bi)) { best = ob; bi = oi; }
            }
            bidx = __shfl(bi, 0);
        }
        if (bidx == oldIdx) continue;
        if (lane == 0) {
            out[IDX_OFF + row] = (float)bidx;
            out[ENC_OFF + (size_t)row * KCODES + oldIdx] = 0.f;
            out[ENC_OFF + (size_t)row * KCODES + bidx]   = 1.f;
        }
        float eN = emb[(size_t)lane * KCODES + bidx];
        float eO = emb[(size_t)lane * KCODES + oldIdx];
        float xv = xr[lane];
        out[Q_OFF + (size_t)row * DDIM + lane] = eN;
        float dn = eN - xv, dod = eO - xv;
        float delta = dn * dn - dod * dod;
        #pragma unroll
        for (int o = 32; o > 0; o >>= 1) delta += __shfl_down(delta, o);
        if (lane == 0) atomicAdd(out + LOSS_OFF, delta * INV_ND);
    }
}

extern "C" void kernel_launch(void* const* d_in, const int* in_sizes, int n_in,
                              void* d_out, int out_size, void* d_ws, size_t ws_size,
                              hipStream_t stream) {
    const float* x   = (const float*)d_in[0];   // [65536, 64]
    const float* emb = (const float*)d_in[1];   // [64, 2048]
    float* out   = (float*)d_out;
    char*  ws    = (char*)d_ws;
    int*   flags = (int*)(ws + WS_FLAGS_OFF);
    hipLaunchKernelGGL(vq_prep,   dim3(512),         dim3(256), 0, stream, emb, ws, out);
    hipLaunchKernelGGL(vq_main,   dim3(N_ROWS / NB), dim3(256), 0, stream, x, emb, ws, flags, out);
    hipLaunchKernelGGL(vq_refine, dim3(N_ROWS / 32), dim3(256), 0, stream, x, emb, flags, out);
}

// Round 4
// 642.855 us; speedup vs baseline: 1.2331x; 1.1023x over previous
//
#include <hip/hip_runtime.h>

// Problem constants
#define N_ROWS 65536   // 32*2048 rows
#define DDIM   64
#define KCODES 2048
#define NB     128     // rows per block
#define CHUNK  256     // codes per LDS chunk
#define NCHUNK (KCODES / CHUNK)
#define TAU    0.05f   // top-2 gap threshold for fp64 refinement

// d_out layout (float32, concatenated in reference return order)
#define Q_OFF    ((size_t)0)
#define ENC_OFF  ((size_t)N_ROWS * DDIM)                 // 4194304
#define IDX_OFF  (ENC_OFF + (size_t)N_ROWS * KCODES)     // 138412032
#define LOSS_OFF (IDX_OFF + (size_t)N_ROWS)              // 138477568
#define INV_ND (1.0f / ((float)N_ROWS * (float)DDIM))

// d_ws layout (bytes):
//   [0, 524288)        : bf16 B image, 8 chunks x { hi[256][64], lo[256][64] } shorts
//                        (k index stored XOR-swizzled: kk = k ^ ((code&7)<<3))
//   [524288, 532480)   : esq, 2048 floats
//   [532480, 794624)   : flags, 65536 ints
#define WS_ESQ_OFF   (524288)
#define WS_FLAGS_OFF (532480)

typedef __attribute__((ext_vector_type(8))) short short8;
typedef __attribute__((ext_vector_type(4))) float f32x4;

__device__ __forceinline__ unsigned short f2bf(float f) {
    unsigned u = __float_as_uint(f);
    u += 0x7FFFu + ((u >> 16) & 1u);
    return (unsigned short)(u >> 16);
}
__device__ __forceinline__ float bf2f(unsigned short h) {
    return __uint_as_float(((unsigned)h) << 16);
}

// Split embeddings into bf16 hi/lo (swizzled layout) + ||e||^2 + zero loss slot.
__global__ void vq_prep(const float* __restrict__ emb, char* __restrict__ ws,
                        float* __restrict__ out) {
    int t = blockIdx.x * 256 + threadIdx.x;        // [0, 131072)
    int code = t & (KCODES - 1);
    int d    = t >> 11;
    float v = emb[(size_t)d * KCODES + code];
    unsigned short hi = f2bf(v);
    unsigned short lo = f2bf(v - bf2f(hi));
    int ch = code >> 8;
    int lc = code & 255;
    int kk = d ^ ((code & 7) << 3);
    short* base = (short*)ws + (size_t)ch * 32768 + lc * 64 + kk;
    base[0]     = (short)hi;
    base[16384] = (short)lo;
    if (t < KCODES) {
        float s = 0.f;
        for (int dd = 0; dd < DDIM; ++dd) {
            float e = emb[(size_t)dd * KCODES + t];
            s += e * e;
        }
        ((float*)(ws + WS_ESQ_OFF))[t] = s;
    }
    if (t == 0) out[LOSS_OFF] = 0.f;
}

__launch_bounds__(256, 2)
__global__ void vq_main(const float* __restrict__ x, const float* __restrict__ emb,
                        const char* __restrict__ ws, int* __restrict__ flags,
                        float* __restrict__ out) {
    __shared__ __align__(16) short Bs[32768];   // 64 KB: hi[256][64] then lo[256][64]
    const int tid = threadIdx.x;
    const int l = tid & 63, w = tid >> 6;
    const int q = l >> 4, c = l & 15;
    const int r0 = blockIdx.x * NB;
    const float* esq = (const float*)(ws + WS_ESQ_OFF);

    // A fragments: this wave's 32 rows, bf16 hi/lo, resident in registers.
    // A-operand layout: lane holds A[m = l&15][k = q*8 + j].
    short8 ah0[2], ah1[2], al0[2], al1[2];
    #pragma unroll
    for (int rt = 0; rt < 2; ++rt) {
        int row = r0 + w * 32 + rt * 16 + c;
        const float4* xr = (const float4*)(x + (size_t)row * DDIM);
        float4 f0 = xr[q * 2],     f1 = xr[q * 2 + 1];
        float4 f2 = xr[8 + q * 2], f3 = xr[8 + q * 2 + 1];
        float a0[8] = {f0.x,f0.y,f0.z,f0.w,f1.x,f1.y,f1.z,f1.w};
        float a1[8] = {f2.x,f2.y,f2.z,f2.w,f3.x,f3.y,f3.z,f3.w};
        #pragma unroll
        for (int j = 0; j < 8; ++j) {
            unsigned short h0 = f2bf(a0[j]);
            ah0[rt][j] = (short)h0;
            al0[rt][j] = (short)f2bf(a0[j] - bf2f(h0));
            unsigned short h1 = f2bf(a1[j]);
            ah1[rt][j] = (short)h1;
            al1[rt][j] = (short)f2bf(a1[j] - bf2f(h1));
        }
    }

    // Per-slot top-3 values + top-2 indices. Slots = 8 distinct output rows.
    float m1[8], m2[8], m3[8]; int i1[8], i2[8];
    #pragma unroll
    for (int s = 0; s < 8; ++s) {
        m1[s] = 3.4e38f; m2[s] = 3.4e38f; m3[s] = 3.4e38f; i1[s] = 0; i2[s] = 0;
    }

    for (int ch = 0; ch < NCHUNK; ++ch) {
        const int kc = ch * CHUNK;
        // Raw barrier (NO vmcnt drain): readers of the previous chunk are done
        // (lgkmcnt(0) forces their pending ds_reads to have landed in regs);
        // the in-flight nt zero-stores keep streaming across chunks instead of
        // being re-convoyed 8x by __syncthreads' vmcnt(0).
        __builtin_amdgcn_sched_barrier(0);
        asm volatile("s_waitcnt lgkmcnt(0)" ::: "memory");
        __builtin_amdgcn_s_barrier();
        __builtin_amdgcn_sched_barrier(0);
        // Stage 64 KB bf16 chunk from ws (linear, conflict-free)
        {
            const int4* g4 = (const int4*)(ws + (size_t)ch * 65536);
            int4* s4 = (int4*)Bs;
            #pragma unroll
            for (int i = 0; i < 16; ++i) s4[i * 256 + tid] = g4[i * 256 + tid];
        }
        __builtin_amdgcn_sched_barrier(0);
        asm volatile("s_waitcnt lgkmcnt(0)" ::: "memory");   // ds_writes visible
        __builtin_amdgcn_s_barrier();
        __builtin_amdgcn_sched_barrier(0);

        // 16 code-tiles of 16; 3-term bf16-split MFMA (hi*hi + hi*lo + lo*hi).
        // Two nontemporal zero-stores per tile (32 total = this chunk's 128x256
        // one-hot slab): nt avoids L2 allocation so the ws image stays
        // L2-resident for the next staging round, and interleaving spreads
        // store-queue pressure under the MFMA work.
        const int swz = (c & 7) << 3;
        float* ebase = out + ENC_OFF + (size_t)r0 * KCODES + kc;
        const f32x4 z = {0.f, 0.f, 0.f, 0.f};
        for (int t = 0; t < 16; ++t) {
            #pragma unroll
            for (int jj = 0; jj < 2; ++jj) {
                int s   = (t * 2 + jj) * 256 + tid;
                int row = s >> 6;
                int c4  = s & 63;
                __builtin_nontemporal_store(
                    z, (f32x4*)(ebase + (size_t)row * KCODES + (c4 << 2)));
            }
            int codeL = t * 16 + c;
            const short* ph = Bs + codeL * 64;
            const short* pl = ph + 16384;
            int k0 = (q * 8) ^ swz;
            int k1 = (32 + q * 8) ^ swz;
            short8 bh0 = *(const short8*)(ph + k0);
            short8 bh1 = *(const short8*)(ph + k1);
            short8 bl0 = *(const short8*)(pl + k0);
            short8 bl1 = *(const short8*)(pl + k1);
            int   kidx = kc + t * 16 + c;
            float eq   = esq[kidx];
            #pragma unroll
            for (int rt = 0; rt < 2; ++rt) {
                f32x4 acc = {0.f, 0.f, 0.f, 0.f};
                acc = __builtin_amdgcn_mfma_f32_16x16x32_bf16(ah0[rt], bh0, acc, 0, 0, 0);
                acc = __builtin_amdgcn_mfma_f32_16x16x32_bf16(ah1[rt], bh1, acc, 0, 0, 0);
                acc = __builtin_amdgcn_mfma_f32_16x16x32_bf16(ah0[rt], bl0, acc, 0, 0, 0);
                acc = __builtin_amdgcn_mfma_f32_16x16x32_bf16(ah1[rt], bl1, acc, 0, 0, 0);
                acc = __builtin_amdgcn_mfma_f32_16x16x32_bf16(al0[rt], bh0, acc, 0, 0, 0);
                acc = __builtin_amdgcn_mfma_f32_16x16x32_bf16(al1[rt], bh1, acc, 0, 0, 0);
                #pragma unroll
                for (int g = 0; g < 4; ++g) {
                    float dist = fmaf(-2.f, acc[g], eq);   // + ||x||^2 omitted (row-const)
                    int s = rt * 4 + g;
                    bool b1 = dist < m1[s];
                    bool b2 = dist < m2[s];
                    bool b3 = dist < m3[s];
                    // top-3 insert (strict < keeps lower kidx on ties; kidx ascends per lane)
                    m3[s] = b2 ? m2[s] : (b3 ? dist : m3[s]);
                    m2[s] = b1 ? m1[s] : (b2 ? dist : m2[s]);
                    i2[s] = b1 ? i1[s] : (b2 ? kidx : i2[s]);
                    m1[s] = b1 ? dist : m1[s];
                    i1[s] = b1 ? kidx : i1[s];
                }
            }
        }
    }

    __syncthreads();   // FULL drain (vmcnt0): all zero-stores globally ordered
                       // before the 1.0 writes below; Bs dead -> reuse for reduction
    float* red  = (float*)Bs;                 // [128 rows][16 cols][5]: m1,i1,m2,i2,m3
    int*   indS = (int*)(red + 10240);        // [128]
    float* lred = red + 10240 + 128;          // [4]

    // C/D layout: col = l&15, row = q*4 + reg  [m89]
    #pragma unroll
    for (int rt = 0; rt < 2; ++rt)
        #pragma unroll
        for (int g = 0; g < 4; ++g) {
            int lrow = w * 32 + rt * 16 + q * 4 + g;
            float* p = red + (size_t)(lrow * 16 + c) * 5;
            int s = rt * 4 + g;
            p[0] = m1[s];
            p[1] = (float)i1[s];
            p[2] = m2[s];
            p[3] = (float)i2[s];
            p[4] = m3[s];
        }
    __syncthreads();

    // Per-row scan across the 16 col-lanes: global top-3 values + top-2 indices.
    // Any code outside {gi1,gi2} has approx dist >= gm3; if gm3-gm1 >= TAU the
    // exact argmin is provably in {gi1,gi2} -> cheap pair-mode refine.
    if (tid < NB) {
        int row = tid;
        const float* p = red + (size_t)row * 80;
        float gm1 = 3.4e38f, gm2v = 3.4e38f, gm3 = 3.4e38f;
        int gi1 = 0x7fffffff, gi2 = 0x7fffffff;
        for (int t = 0; t < 16; ++t) {
            float v1 = p[t * 5 + 0], v2 = p[t * 5 + 2], v3 = p[t * 5 + 4];
            int   j1 = (int)p[t * 5 + 1], j2 = (int)p[t * 5 + 3];
            // insert (v1, j1)
            if (v1 < gm1 || (v1 == gm1 && j1 < gi1)) {
                gm3 = gm2v; gm2v = gm1; gi2 = gi1; gm1 = v1; gi1 = j1;
            } else if (v1 < gm2v || (v1 == gm2v && j1 < gi2)) {
                gm3 = gm2v; gm2v = v1; gi2 = j1;
            } else if (v1 < gm3) gm3 = v1;
            // insert (v2, j2)  (v2 >= v1, so it can't displace what v1 just set wrongly)
            if (v2 < gm1 || (v2 == gm1 && j2 < gi1)) {
                gm3 = gm2v; gm2v = gm1; gi2 = gi1; gm1 = v2; gi1 = j2;
            } else if (v2 < gm2v || (v2 == gm2v && j2 < gi2)) {
                gm3 = gm2v; gm2v = v2; gi2 = j2;
            } else if (v2 < gm3) gm3 = v2;
            // v3 can only be a global 3rd-value candidate (its col already holds 2 better)
            if (v3 < gm3) gm3 = v3;
        }
        int gr = r0 + row;
        out[IDX_OFF + gr] = (float)gi1;
        int f = 0;
        if (gm2v - gm1 < TAU) f = (gm3 - gm1 < TAU) ? 1 : ((gi2 << 2) | 2);
        flags[gr] = f;
        indS[row] = gi1;
        out[ENC_OFF + (size_t)gr * KCODES + gi1] = 1.0f;  // after zero-drain barrier
    }
    __syncthreads();

    // Quantized rows + commitment-loss partial (exact fp32 inputs)
    float lpart = 0.f;
    for (int i = tid; i < NB * (DDIM / 4); i += 256) {
        int row = i >> 4;
        int d4  = (i & 15) << 2;
        int idx = indS[row];
        int gr  = r0 + row;
        float4 qv;
        qv.x = emb[(size_t)(d4 + 0) * KCODES + idx];
        qv.y = emb[(size_t)(d4 + 1) * KCODES + idx];
        qv.z = emb[(size_t)(d4 + 2) * KCODES + idx];
        qv.w = emb[(size_t)(d4 + 3) * KCODES + idx];
        *(float4*)(out + Q_OFF + (size_t)gr * DDIM + d4) = qv;
        float4 xv = *(const float4*)(x + (size_t)gr * DDIM + d4);
        float dx = qv.x - xv.x, dy = qv.y - xv.y, dz = qv.z - xv.z, dw = qv.w - xv.w;
        lpart += dx * dx + dy * dy + dz * dz + dw * dw;
    }
    #pragma unroll
    for (int o = 32; o > 0; o >>= 1) lpart += __shfl_down(lpart, o);
    if ((tid & 63) == 0) lred[tid >> 6] = lpart;
    __syncthreads();
    if (tid == 0)
        atomicAdd(out + LOSS_OFF, (lred[0] + lred[1] + lred[2] + lred[3]) * INV_ND);
}

// Exact fp64 argmin for rows whose top-2 gap was below TAU.
// flags: 0 = clean; 1 = full 2048-code fp64 scan (two gaps below TAU, rare);
//        (i2<<2)|2 = pair mode: exact compare {current idx, i2} only.
__global__ void vq_refine(const float* __restrict__ x, const float* __restrict__ emb,
                          const int* __restrict__ flags, float* __restrict__ out) {
    const int lane = threadIdx.x & 63;
    const int wid  = threadIdx.x >> 6;
    for (int rr = 0; rr < 8; ++rr) {
        int row = (blockIdx.x * 4 + wid) * 8 + rr;
        int f = flags[row];
        if (f == 0) continue;                 // wave-uniform
        const float* xr = x + (size_t)row * DDIM;
        int oldIdx = (int)out[IDX_OFF + row];
        int bidx;
        if (f != 1) {
            // Pair mode: lane = dim; fp64 dist = ||e||^2 - 2 x.e (same formula as scan)
            int cand = f >> 2;
            double xd = (double)xr[lane];
            double ea = (double)emb[(size_t)lane * KCODES + oldIdx];
            double eb = (double)emb[(size_t)lane * KCODES + cand];
            double sa = xd * ea, sb = xd * eb;
            double qa = ea * ea, qb = eb * eb;
            #pragma unroll
            for (int o = 32; o > 0; o >>= 1) {
                sa += __shfl_down(sa, o);
                sb += __shfl_down(sb, o);
                qa += __shfl_down(qa, o);
                qb += __shfl_down(qb, o);
            }
            double dA = __shfl(qa - 2.0 * sa, 0);
            double dB = __shfl(qb - 2.0 * sb, 0);
            bidx = (dB < dA || (dB == dA && cand < oldIdx)) ? cand : oldIdx;
        } else {
            double best = 1e300; int bi = 0x7fffffff;
            for (int k = lane; k < KCODES; k += 64) {
                double s = 0.0, ee = 0.0;
                for (int d = 0; d < DDIM; ++d) {
                    double e = (double)emb[(size_t)d * KCODES + k];
                    s  = fma((double)xr[d], e, s);
                    ee = fma(e, e, ee);
                }
                double dist = ee - 2.0 * s;
                if (dist < best) { best = dist; bi = k; }
            }
            #pragma unroll
            for (int o = 32; o > 0; o >>= 1) {
                double ob = __shfl_down(best, o);
                int    oi = __shfl_down(bi, o);
                if (ob < best || (ob == best && oi < bi)) { best = ob; bi = oi; }
            }
            bidx = __shfl(bi, 0);
        }
        if (bidx == oldIdx) continue;
        if (lane == 0) {
            out[IDX_OFF + row] = (float)bidx;
            out[ENC_OFF + (size_t)row * KCODES + oldIdx] = 0.f;
            out[ENC_OFF + (size_t)row * KCODES + bidx]   = 1.f;
        }
        float eN = emb[(size_t)lane * KCODES + bidx];
        float eO = emb[(size_t)lane * KCODES + oldIdx];
        float xv = xr[lane];
        out[Q_OFF + (size_t)row * DDIM + lane] = eN;
        float dn = eN - xv, dod = eO - xv;
        float delta = dn * dn - dod * dod;
        #pragma unroll
        for (int o = 32; o > 0; o >>= 1) delta += __shfl_down(delta, o);
        if (lane == 0) atomicAdd(out + LOSS_OFF, delta * INV_ND);
    }
}

extern "C" void kernel_launch(void* const* d_in, const int* in_sizes, int n_in,
                              void* d_out, int out_size, void* d_ws, size_t ws_size,
                              hipStream_t stream) {
    const float* x   = (const float*)d_in[0];   // [65536, 64]
    const float* emb = (const float*)d_in[1];   // [64, 2048]
    float* out   = (float*)d_out;
    char*  ws    = (char*)d_ws;
    int*   flags = (int*)(ws + WS_FLAGS_OFF);
    hipLaunchKernelGGL(vq_prep,   dim3(512),         dim3(256), 0, stream, emb, ws, out);
    hipLaunchKernelGGL(vq_main,   dim3(N_ROWS / NB), dim3(256), 0, stream, x, emb, ws, flags, out);
    hipLaunchKernelGGL(vq_refine, dim3(N_ROWS / 32), dim3(256), 0, stream, x, emb, flags, out);
}